// Round 9
// baseline (413.452 us; speedup 1.0000x reference)
//
#include <hip/hip_runtime.h>

typedef unsigned short u16;
typedef unsigned long long u64;
typedef float f32x4 __attribute__((ext_vector_type(4)));
typedef __bf16 bf16x4 __attribute__((ext_vector_type(4)));
typedef __bf16 bf16x8 __attribute__((ext_vector_type(8)));
typedef u16 u16x8 __attribute__((ext_vector_type(8)));

#define QSCALE 0.18033688011112042f   /* 0.125 * log2(e) */

// ---------- helpers ----------
__device__ __forceinline__ u16 f2bf(float f) {
  unsigned int u = __float_as_uint(f);
  u += 0x7fffu + ((u >> 16) & 1u);   // round-to-nearest-even
  return (u16)(u >> 16);
}

// async global->LDS, 16B per lane; HW dest = readfirstlane(l) + lane*16.
__device__ __forceinline__ void async16(const void* g, void* l) {
  __builtin_amdgcn_global_load_lds(
      (__attribute__((address_space(1))) void*)g,
      (__attribute__((address_space(3))) void*)l,
      16, 0, 0);
}

__device__ __forceinline__ f32x4 mfma16(bf16x8 a, bf16x8 b, f32x4 c) {
  return __builtin_amdgcn_mfma_f32_16x16x32_bf16(a, b, c, 0, 0, 0);
}

// ---------- cvt (7 tensors) + mask packing, one launch ----------
struct CvtArgs {
  const float* src[7];
  u16* dst[7];
  const int* mask;
  u64* pm;
};

__global__ __launch_bounds__(256) void cvt_kernel(CvtArgs a) {
  int z = blockIdx.z;
  int tid0 = blockIdx.x * 256 + threadIdx.x;
  if (z < 7) {
    int n = (z < 3) ? 4194304 : 1048576;
    int base = tid0 * 8;
    if (base >= n) return;
    const float* s = a.src[z] + base;
    f32x4 x0 = *(const f32x4*)s;
    f32x4 x1 = *(const f32x4*)(s + 4);
    u16x8 pk;
    pk[0]=f2bf(x0[0]); pk[1]=f2bf(x0[1]); pk[2]=f2bf(x0[2]); pk[3]=f2bf(x0[3]);
    pk[4]=f2bf(x1[0]); pk[5]=f2bf(x1[1]); pk[6]=f2bf(x1[2]); pk[7]=f2bf(x1[3]);
    *(u16x8*)(a.dst[z] + base) = pk;
  } else {
    if (tid0 >= 131072) return;              // B*S*(S/64)
    const int4* src = (const int4*)(a.mask + (size_t)tid0 * 64);
    u64 bits = 0ull;
#pragma unroll
    for (int j = 0; j < 16; ++j) {
      int4 v = src[j];
      if (v.x) bits |= 1ull << (4 * j + 0);
      if (v.y) bits |= 1ull << (4 * j + 1);
      if (v.z) bits |= 1ull << (4 * j + 2);
      if (v.w) bits |= 1ull << (4 * j + 3);
    }
    a.pm[tid0] = bits;
  }
}

// ---------- GEMM (m97 structure) ----------
// mode 0: out (B,H,S,Dh)  mode 1: out (B,H,Dh,S)  mode 2: MxN f32 atomic-add
__device__ __forceinline__ void gemm_body(const u16* __restrict__ A,
                                          const u16* __restrict__ W,
                                          const float* __restrict__ bias,
                                          void* __restrict__ outraw, int mode,
                                          float oscale, int kbeg, int kend,
                                          float bscale) {
  alignas(16) __shared__ u16 lA[128 * 32];
  alignas(16) __shared__ u16 lB[128 * 32];
  const int tid = threadIdx.x;
  const int lane = tid & 63, wv = tid >> 6;
  const int wm = wv >> 1, wn = wv & 1;
  const int m0 = blockIdx.y * 128, n0 = blockIdx.x * 128;
  const int l15 = lane & 15, quad = lane >> 4;
  const int srow = lane >> 2;
  const int scol = (lane & 3) * 8;

  f32x4 acc[4][4] = {};

  for (int k0 = kbeg; k0 < kend; k0 += 32) {
#pragma unroll
    for (int t = 0; t < 2; ++t) {
      int rb = (wv * 2 + t) * 16;
      async16(A + (size_t)(m0 + rb + srow) * 1024 + k0 + scol, (char*)lA + rb * 64);
      async16(W + (size_t)(n0 + rb + srow) * 1024 + k0 + scol, (char*)lB + rb * 64);
    }
    __syncthreads();
    bf16x8 af[4], bfr[4];
#pragma unroll
    for (int i = 0; i < 4; ++i) {
      af[i]  = *(const bf16x8*)(lA + (wm * 64 + i * 16 + l15) * 32 + quad * 8);
      bfr[i] = *(const bf16x8*)(lB + (wn * 64 + i * 16 + l15) * 32 + quad * 8);
    }
#pragma unroll
    for (int i = 0; i < 4; ++i)
#pragma unroll
      for (int j = 0; j < 4; ++j)
        acc[i][j] = mfma16(af[i], bfr[j], acc[i][j]);
    __syncthreads();
  }

#pragma unroll
  for (int i = 0; i < 4; ++i) {
    int mbase = m0 + wm * 64 + i * 16 + quad * 4;
#pragma unroll
    for (int j = 0; j < 4; ++j) {
      int n = n0 + wn * 64 + j * 16 + l15;
      float bv = bias[n] * bscale;
#pragma unroll
      for (int r = 0; r < 4; ++r) {
        int m = mbase + r;
        float val = (acc[i][j][r] + bv) * oscale;
        if (mode == 0) {
          int b = m >> 11, s = m & 2047, h = n >> 6, dh = n & 63;
          ((u16*)outraw)[((((size_t)b * 16 + h) * 2048 + s) << 6) + dh] = f2bf(val);
        } else if (mode == 1) {
          int b = m >> 11, s = m & 2047, h = n >> 6, dh = n & 63;
          ((u16*)outraw)[((((size_t)b * 16 + h) * 64 + dh) << 11) + s] = f2bf(val);
        } else {
          unsafeAtomicAdd(&((float*)outraw)[(size_t)m * 1024 + n], val);
        }
      }
    }
  }
}

__global__ __launch_bounds__(256) void gemm_qkv_kernel(
    const u16* __restrict__ qb, const u16* __restrict__ kb, const u16* __restrict__ vb,
    const u16* __restrict__ Wqb, const float* __restrict__ bq,
    const u16* __restrict__ Wkb, const float* __restrict__ bk,
    const u16* __restrict__ Wvb, const float* __restrict__ bv,
    u16* __restrict__ qp, u16* __restrict__ kp, u16* __restrict__ vt) {
  if (blockIdx.z == 0)      gemm_body(qb, Wqb, bq, qp, 0, QSCALE, 0, 1024, 1.0f);
  else if (blockIdx.z == 1) gemm_body(kb, Wkb, bk, kp, 0, 1.0f, 0, 1024, 1.0f);
  else                      gemm_body(vb, Wvb, bv, vt, 1, 1.0f, 0, 1024, 1.0f);
}

// split-K=2: z picks K-half; both halves atomic-add into zeroed f32 out.
__global__ __launch_bounds__(256) void gemm_o_kernel(
    const u16* __restrict__ joint, const u16* __restrict__ Wob,
    const float* __restrict__ bo, float* __restrict__ out) {
  int z = blockIdx.z;
  gemm_body(joint, Wob, bo, out, 2, 1.0f, z * 512, z * 512 + 512, z ? 0.0f : 1.0f);
}

// ---------- flash attention, S^T formulation, 32 q/wave, split-K=2 ----------
// grid (16,16,4): z = b*2 + split; split s covers kv tiles [16s,16s+16).
// Fixed-max softmax => unnormalized O and l are additive across splits:
// epilogue atomically accumulates into O_acc (f32, pre-zeroed) and l_acc.
__global__ __launch_bounds__(256, 3) void attn_kernel(
    const u16* __restrict__ qp, const u16* __restrict__ kp,
    const u16* __restrict__ vt, const u64* __restrict__ pm,
    float* __restrict__ O_acc, float* __restrict__ l_acc) {
  alignas(16) __shared__ u16 kbuf[2][4096];     // 2 x 8 KB
  alignas(16) __shared__ u16 vbuf[2][4096];     // 2 x 8 KB
  alignas(16) __shared__ u16 pbuf[4][2][1024];  // per wave x group P^T

  const int tid = threadIdx.x, lane = tid & 63, wv = tid >> 6;
  const int quad = lane >> 4, l15 = lane & 15;
  const int q0 = blockIdx.x * 128;
  const int h = blockIdx.y;
  const int b = blockIdx.z >> 1, sp = blockIdx.z & 1;
  const int kt0 = sp * 16, kt1 = kt0 + 16;
  const size_t head_off = ((size_t)b * 16 + h) * 2048 * 64;
  const u16* Qh = qp + head_off;   // [2048][64]  (pre-scaled)
  const u16* Kh = kp + head_off;   // [2048][64]
  const u16* Vh = vt + head_off;   // [64][2048]  (dh-major)
  const int qr0 = q0 + wv * 32 + l15;          // group 0 q row; group 1 = +16
  const u64* pmq = pm + ((size_t)b * 2048 + qr0) * 32;   // group1 at +512

  bf16x8 qf[2][2];
#pragma unroll
  for (int g = 0; g < 2; ++g) {
    const u16* qrow = Qh + (size_t)(qr0 + g * 16) * 64 + quad * 8;
    qf[g][0] = *(const bf16x8*)(qrow);
    qf[g][1] = *(const bf16x8*)(qrow + 32);
  }

  const int sd0 = tid, sd1 = 256 + tid;
  const int snt0 = sd0 >> 7, shalf0 = (sd0 >> 6) & 1, sl60 = sd0 & 63;
  const int snt1 = sd1 >> 7, shalf1 = (sd1 >> 6) & 1, sl61 = sd1 & 63;
  const u16* kg0 = Kh + (size_t)(snt0 * 16 + (sl60 & 15)) * 64 + shalf0 * 32 + (sl60 >> 4) * 8;
  const u16* kg1 = Kh + (size_t)(snt1 * 16 + (sl61 & 15)) * 64 + shalf1 * 32 + (sl61 >> 4) * 8;
  const int vb0 = sd0 >> 6, vb1 = sd1 >> 6;
  const u16* vg0 = Vh + (size_t)((vb0 >> 1) * 16 + (sl60 & 15)) * 2048 + (vb0 & 1) * 32 + (sl60 >> 4) * 8;
  const u16* vg1 = Vh + (size_t)((vb1 >> 1) * 16 + (sl61 & 15)) * 2048 + (vb1 & 1) * 32 + (sl61 >> 4) * 8;

  f32x4 O[2][4] = {};
  f32x4 lacc[2] = {};

  // prologue: stage tile kt0 into buffer 0 (kt0 is even)
  {
    const size_t kadv = (size_t)kt0 * 4096;
    const int vadv = kt0 * 64;
    async16(kg0 + kadv, (char*)kbuf[0] + sd0 * 16);
    async16(kg1 + kadv, (char*)kbuf[0] + sd1 * 16);
    async16(vg0 + vadv, (char*)vbuf[0] + sd0 * 16);
    async16(vg1 + vadv, (char*)vbuf[0] + sd1 * 16);
  }

  for (int kt = kt0; kt < kt1; ++kt) {
    __syncthreads();

    if (kt != kt1 - 1) {
      const size_t kadv = (size_t)(kt + 1) * 4096;
      const int vadv = (kt + 1) * 64;
      char* kd = (char*)kbuf[(kt + 1) & 1];
      char* vd = (char*)vbuf[(kt + 1) & 1];
      async16(kg0 + kadv, kd + sd0 * 16);
      async16(kg1 + kadv, kd + sd1 * 16);
      async16(vg0 + vadv, vd + sd0 * 16);
      async16(vg1 + vadv, vd + sd1 * 16);
    }

    u64 w0 = pmq[kt], w1 = pmq[kt + 512];
    const u16* kc = kbuf[kt & 1];
    const u16* vc = vbuf[kt & 1];

    bf16x8 kf[8];
#pragma unroll
    for (int nt = 0; nt < 4; ++nt) {
      kf[2 * nt]     = *(const bf16x8*)(kc + nt * 1024 + lane * 8);
      kf[2 * nt + 1] = *(const bf16x8*)(kc + nt * 1024 + 512 + lane * 8);
    }

    f32x4 S[2][4];
#pragma unroll
    for (int g = 0; g < 2; ++g)
#pragma unroll
      for (int nt = 0; nt < 4; ++nt) {
        f32x4 z = {};
        z = mfma16(kf[2 * nt], qf[g][0], z);
        S[g][nt] = mfma16(kf[2 * nt + 1], qf[g][1], z);
      }

#pragma unroll
    for (int g = 0; g < 2; ++g) {
      u64 word = g ? w1 : w0;
      unsigned int wlo = (unsigned int)word, whi = (unsigned int)(word >> 32);
#pragma unroll
      for (int nt = 0; nt < 4; ++nt) {
        unsigned int hw = (nt < 2) ? wlo : whi;
        unsigned int nib = hw >> ((nt & 1) * 16 + quad * 4);
#pragma unroll
        for (int r = 0; r < 4; ++r) {
          float pe = __builtin_amdgcn_exp2f(S[g][nt][r]);
          S[g][nt][r] = ((nib >> r) & 1u) ? pe : 0.f;
        }
        lacc[g] += S[g][nt];
        bf16x4 pv = __builtin_convertvector(S[g][nt], bf16x4);
        int t4 = 4 * nt + quad;
        int ks = t4 >> 3, qd = (t4 & 7) >> 1;
        u16* pw = pbuf[wv][g] + ks * 512 + qd * 128 + l15 * 8 + (t4 & 1) * 4;
        *(u64*)pw = *(const u64*)&pv;
      }
    }

    bf16x8 vf[8];
#pragma unroll
    for (int nt = 0; nt < 4; ++nt) {
      vf[2 * nt]     = *(const bf16x8*)(vc + (nt * 2) * 512 + lane * 8);
      vf[2 * nt + 1] = *(const bf16x8*)(vc + (nt * 2 + 1) * 512 + lane * 8);
    }
    asm volatile("s_waitcnt lgkmcnt(0)" ::: "memory");

#pragma unroll
    for (int ks = 0; ks < 2; ++ks) {
      bf16x8 pf0 = *(const bf16x8*)(pbuf[wv][0] + ks * 512 + lane * 8);
      bf16x8 pf1 = *(const bf16x8*)(pbuf[wv][1] + ks * 512 + lane * 8);
#pragma unroll
      for (int nt = 0; nt < 4; ++nt) {
        O[0][nt] = mfma16(vf[2 * nt + ks], pf0, O[0][nt]);
        O[1][nt] = mfma16(vf[2 * nt + ks], pf1, O[1][nt]);
      }
    }
  }

  // ---- epilogue: atomic accumulate unnormalized partials ----
  float lsum[2];
#pragma unroll
  for (int g = 0; g < 2; ++g) {
    float l = (lacc[g][0] + lacc[g][1]) + (lacc[g][2] + lacc[g][3]);
    l += __shfl_xor(l, 16, 64);
    l += __shfl_xor(l, 32, 64);
    lsum[g] = l;
  }
  size_t obase = (((size_t)b * 16 + h) * 2048 + qr0) * 64;
#pragma unroll
  for (int g = 0; g < 2; ++g)
#pragma unroll
    for (int nt = 0; nt < 4; ++nt)
#pragma unroll
      for (int r = 0; r < 4; ++r)
        unsafeAtomicAdd(O_acc + obase + (size_t)g * 1024 + nt * 16 + quad * 4 + r,
                        O[g][nt][r]);
  if (quad == 0) {
    size_t lbase = ((size_t)b * 16 + h) * 2048 + qr0;
    unsafeAtomicAdd(l_acc + lbase, lsum[0]);
    unsafeAtomicAdd(l_acc + lbase + 16, lsum[1]);
  }
}

// ---------- normalize O_acc/l_acc -> joint bf16 ----------
__global__ __launch_bounds__(256) void norm_kernel(
    const float* __restrict__ O_acc, const float* __restrict__ l_acc,
    u16* __restrict__ joint) {
  int idx = blockIdx.x * 256 + threadIdx.x;     // 0..524287, 8 dh each
  int row = idx >> 3, c = idx & 7;              // row over B*H*S
  float inv = 1.0f / l_acc[row];
  const f32x4* src = (const f32x4*)(O_acc + (size_t)idx * 8);
  f32x4 a = src[0] * inv, d = src[1] * inv;
  int b = row >> 15, h = (row >> 11) & 15, q = row & 2047;
  u16x8 pk;
  pk[0]=f2bf(a[0]); pk[1]=f2bf(a[1]); pk[2]=f2bf(a[2]); pk[3]=f2bf(a[3]);
  pk[4]=f2bf(d[0]); pk[5]=f2bf(d[1]); pk[6]=f2bf(d[2]); pk[7]=f2bf(d[3]);
  *(u16x8*)(joint + ((size_t)(b * 2048 + q)) * 1024 + h * 64 + c * 8) = pk;
}

// ---------- launch ----------
extern "C" void kernel_launch(void* const* d_in, const int* in_sizes, int n_in,
                              void* d_out, int out_size, void* d_ws, size_t ws_size,
                              hipStream_t stream) {
  const float* q  = (const float*)d_in[0];
  const float* k  = (const float*)d_in[1];
  const float* v  = (const float*)d_in[2];
  const int* mask = (const int*)d_in[3];
  const float* Wq = (const float*)d_in[4];
  const float* bq = (const float*)d_in[5];
  const float* Wk = (const float*)d_in[6];
  const float* bk = (const float*)d_in[7];
  const float* Wv = (const float*)d_in[8];
  const float* bv = (const float*)d_in[9];
  const float* Wo = (const float*)d_in[10];
  const float* bo = (const float*)d_in[11];
  float* out = (float*)d_out;

  u16* w = (u16*)d_ws;
  u16* qp    = w;                         // (B,H,S,Dh)
  u16* kp    = w + 4194304;               // (B,H,S,Dh)
  u16* vt    = w + 8388608;               // (B,H,Dh,S)
  u16* qb    = w + 12582912;              // bf16 q; joint aliases after attn
  u16* kb    = w + 16777216;              // dead after qkv -> O_acc lives here
  u16* vb    = w + 20971520;
  u16* Wqb   = w + 25165824;              // dead after qkv -> l_acc lives here
  u16* Wkb   = w + 26214400;
  u16* Wvb   = w + 27262976;
  u16* Wob   = w + 28311552;              // needed by gemm_o (not overwritten)
  u64* pm    = (u64*)(w + 29360128);
  u16* joint = qb;
  float* O_acc = (float*)(w + 16777216);  // 16 MiB, exactly kb+vb span
  float* l_acc = (float*)(w + 25165824);  // 256 KiB, ex-Wqb span

  CvtArgs ca;
  ca.src[0] = q;  ca.dst[0] = qb;
  ca.src[1] = k;  ca.dst[1] = kb;
  ca.src[2] = v;  ca.dst[2] = vb;
  ca.src[3] = Wq; ca.dst[3] = Wqb;
  ca.src[4] = Wk; ca.dst[4] = Wkb;
  ca.src[5] = Wv; ca.dst[5] = Wvb;
  ca.src[6] = Wo; ca.dst[6] = Wob;
  ca.mask = mask; ca.pm = pm;

  hipMemsetAsync(d_out, 0, (size_t)out_size * 4, stream);          // for gemm_o atomics
  cvt_kernel<<<dim3(2048, 1, 8), dim3(256), 0, stream>>>(ca);
  gemm_qkv_kernel<<<dim3(8, 32, 3), dim3(256), 0, stream>>>(
      qb, kb, vb, Wqb, bq, Wkb, bk, Wvb, bv, qp, kp, vt);
  // zero O_acc + l_acc (contiguous) now that qkv no longer needs kb/vb/Wqb
  hipMemsetAsync((void*)(w + 16777216), 0, (size_t)17039360, stream);
  attn_kernel<<<dim3(16, 16, 4), dim3(256), 0, stream>>>(qp, kp, vt, pm, O_acc, l_acc);
  norm_kernel<<<dim3(2048), dim3(256), 0, stream>>>(O_acc, l_acc, joint);
  gemm_o_kernel<<<dim3(8, 32, 2), dim3(256), 0, stream>>>(joint, Wob, bo, out);
}